// Round 7
// baseline (164.224 us; speedup 1.0000x reference)
//
#include <hip/hip_runtime.h>
#include <hip/hip_bf16.h>

#define BB    4
#define NN    16384
#define DD    128
#define HH    8
#define DHH   64
#define INNER 512
#define PC    128         // K^T V row-chunks per batch (K1 main grid = BB*PC = 512)

typedef __attribute__((ext_vector_type(8))) short bf16x8;
typedef __attribute__((ext_vector_type(4))) short short4_t;
typedef __attribute__((ext_vector_type(4))) float f32x4;
typedef unsigned short ushort_t;

#define MFMA(a, b, c) __builtin_amdgcn_mfma_f32_16x16x32_bf16((a), (b), (c), 0, 0, 0)

#define ASM_LGKM0() asm volatile("s_waitcnt lgkmcnt(0)" ::: "memory")
#define FENCE()     __builtin_amdgcn_sched_barrier(0)
#define BAR()       __builtin_amdgcn_s_barrier()
#define NTL(p)      __builtin_nontemporal_load(p)

// fp32 -> bf16 round-to-nearest-even
__device__ __forceinline__ short f2bf(float x) {
    union { float f; unsigned u; } v; v.f = x;
    unsigned u = v.u;
    u += 0x7fffu + ((u >> 16) & 1u);
    return (short)(u >> 16);
}

__device__ __forceinline__ float bf2f(ushort_t us) {
    union { unsigned u; float f; } v;
    v.u = ((unsigned)us) << 16;
    return v.f;
}

__device__ __forceinline__ bf16x8 load_row8(const float* __restrict__ p) {
    f32x4 a = *(const f32x4*)p;
    f32x4 b = *(const f32x4*)(p + 4);
    bf16x8 r;
    r[0] = f2bf(a[0]); r[1] = f2bf(a[1]); r[2] = f2bf(a[2]); r[3] = f2bf(a[3]);
    r[4] = f2bf(b[0]); r[5] = f2bf(b[1]); r[6] = f2bf(b[2]); r[7] = f2bf(b[3]);
    return r;
}

// nt variant: streaming read (no L1 allocation) for single-use data
__device__ __forceinline__ bf16x8 load_row8_nt(const float* __restrict__ p) {
    f32x4 a = NTL((const f32x4*)p);
    f32x4 b = NTL((const f32x4*)(p + 4));
    bf16x8 r;
    r[0] = f2bf(a[0]); r[1] = f2bf(a[1]); r[2] = f2bf(a[2]); r[3] = f2bf(a[3]);
    r[4] = f2bf(b[0]); r[5] = f2bf(b[1]); r[6] = f2bf(b[2]); r[7] = f2bf(b[3]);
    return r;
}

__device__ __forceinline__ bf16x8 load_col8(const float* __restrict__ p, int stride) {
    bf16x8 r;
#pragma unroll
    for (int j = 0; j < 8; ++j) r[j] = f2bf(p[(size_t)j * stride]);
    return r;
}

// ---------------------------------------------------------------------------
// K1: blocks [16,528): partial S[b] = keys^T @ values over a 128-row chunk.
//   R7: keys/values staged with NON-TEMPORAL loads. Theory: f32x4 wave-loads
//   touch 16 lines each; L1 MSHR slots (~32/CU) cap concurrency at ~2
//   loads/CU -> 4096 lines x 375ns/32 ~ 48us, matching the measured 41.5us
//   regardless of pipeline structure. nt bypasses L1 allocation (deeper
//   miss path). Pipeline structure from R6 kept. Bit-exact numerics.
// Blocks [0,16): head-factor producers + G zeroing.
// ---------------------------------------------------------------------------
__global__ __launch_bounds__(512, 4) void k1_partialS_ab(
        const float* __restrict__ keys, const float* __restrict__ vals,
        const float* __restrict__ Wq, const float* __restrict__ Wk,
        const float* __restrict__ Wo,
        ushort_t* __restrict__ partial, ushort_t* __restrict__ Abf,
        ushort_t* __restrict__ BTbf, float* __restrict__ G) {
    const int lane = threadIdx.x & 63;
    const int w    = threadIdx.x >> 6;   // 0..7
    const int ml   = lane & 15;
    const int quad = lane >> 4;

    __shared__ short tK[2][32][132];     // pitch 132: b64-aligned writes
    __shared__ short tV[2][32][132];

    if (blockIdx.x >= 16) {
        const int mb    = blockIdx.x - 16;        // 0..511
        const int b     = mb >> 7;
        const int chunk = mb & (PC - 1);
        const int r0    = chunk * (NN / PC);      // 128 rows per block
        const int mw    = w & 3;
        const int nw    = w >> 2;

        const float* kbase = keys + (size_t)b * NN * DD;
        const float* vbase = vals + (size_t)b * NN * DD;

        const int lin0 = (int)threadIdx.x;
        const int ca0  = (2 * mw + 0) * 16 + ml;
        const int ca1  = (2 * mw + 1) * 16 + ml;

        const int row0 = lin0 >> 5,          row1 = (lin0 + 512) >> 5;
        const int c40  = (lin0 & 31) << 2,   c41  = ((lin0 + 512) & 31) << 2;

        f32x4 acc[2][4];
#pragma unroll
        for (int i = 0; i < 2; ++i)
#pragma unroll
            for (int t = 0; t < 4; ++t) acc[i][t] = (f32x4){0.f, 0.f, 0.f, 0.f};

        f32x4 kpre[2][2], vpre[2][2];        // [slot][it], slot = step & 1

        auto issueL = [&](int sidx, int slot) {
            const float* kp = kbase + (size_t)(r0 + sidx * 32) * DD;
            const float* vp = vbase + (size_t)(r0 + sidx * 32) * DD;
            kpre[slot][0] = NTL((const f32x4*)(kp + (size_t)row0 * DD + c40));
            vpre[slot][0] = NTL((const f32x4*)(vp + (size_t)row0 * DD + c40));
            kpre[slot][1] = NTL((const f32x4*)(kp + (size_t)row1 * DD + c41));
            vpre[slot][1] = NTL((const f32x4*)(vp + (size_t)row1 * DD + c41));
        };

        auto wstage = [&](int slot, int nb) {
#pragma unroll
            for (int it = 0; it < 2; ++it) {
                const int row = it ? row1 : row0;
                const int c4  = it ? c41  : c40;
                short4_t ks, vs;
#pragma unroll
                for (int j = 0; j < 4; ++j) {
                    ks[j] = f2bf(kpre[slot][it][j]);
                    vs[j] = f2bf(vpre[slot][it][j]);
                }
                *(short4_t*)&tK[nb][row][c4] = ks;
                *(short4_t*)&tV[nb][row][c4] = vs;
            }
        };

        auto compute = [&](int cur) {
            bf16x8 a0, a1;
#pragma unroll
            for (int j = 0; j < 8; ++j) {
                a0[j] = tK[cur][quad * 8 + j][ca0];
                a1[j] = tK[cur][quad * 8 + j][ca1];
            }
#pragma unroll
            for (int t = 0; t < 4; ++t) {
                const int cb = (nw * 4 + t) * 16 + ml;
                bf16x8 bf;
#pragma unroll
                for (int j = 0; j < 8; ++j) bf[j] = tV[cur][quad * 8 + j][cb];
                acc[0][t] = MFMA(a0, bf, acc[0][t]);
                acc[1][t] = MFMA(a1, bf, acc[1][t]);
            }
        };

        // ---- pipeline: loads for steps s,s+1 always in flight ----
        issueL(0, 0); issueL(1, 1);
        wstage(0, 0);
        ASM_LGKM0(); FENCE(); BAR();

        // s = 0
        issueL(2, 0);
        compute(0);
        ASM_LGKM0(); FENCE(); BAR();
        wstage(1, 1);
        ASM_LGKM0(); FENCE(); BAR();

        // s = 1
        issueL(3, 1);
        compute(1);
        ASM_LGKM0(); FENCE(); BAR();
        wstage(0, 0);
        ASM_LGKM0(); FENCE(); BAR();

        // s = 2
        compute(0);
        ASM_LGKM0(); FENCE(); BAR();
        wstage(1, 1);
        ASM_LGKM0(); FENCE(); BAR();

        // s = 3
        compute(1);

        ushort_t* outp = partial + (size_t)mb * DD * DD;
#pragma unroll
        for (int i = 0; i < 2; ++i) {
            const int mrow = (2 * mw + i) * 16 + quad * 4;
#pragma unroll
            for (int t = 0; t < 4; ++t) {
                const int col = (nw * 4 + t) * 16 + ml;
#pragma unroll
                for (int r = 0; r < 4; ++r)
                    outp[(size_t)(mrow + r) * DD + col] = (ushort_t)f2bf(acc[i][t][r]);
            }
        }
    } else {
        // ---- head-factor producer (weights only) + G zeroing ----
        const int ab    = blockIdx.x;             // 0..15
        const int h     = ab & 7;
        const int which = ab >> 3;                // 0 -> A_h, 1 -> BT_h
        const float* Wkh = Wk + (size_t)h * DHH * DD;

        // zero G: 16 blocks x 512 threads x 8 floats = 65536 = BB*DD*DD
        {
            const int base = (ab * 512 + (int)threadIdx.x) * 8;
            *(f32x4*)&G[base]     = (f32x4){0.f, 0.f, 0.f, 0.f};
            *(f32x4*)&G[base + 4] = (f32x4){0.f, 0.f, 0.f, 0.f};
        }

        f32x4 acc[8];
#pragma unroll
        for (int t = 0; t < 8; ++t) acc[t] = (f32x4){0.f, 0.f, 0.f, 0.f};

        if (which == 0) {
            const float* Wqh = Wq + (size_t)h * DHH * DD;
#pragma unroll
            for (int kc = 0; kc < 2; ++kc) {
                const int d0 = kc * 32 + quad * 8;
                bf16x8 a = load_col8(Wqh + (size_t)d0 * DD + w * 16 + ml, DD);
#pragma unroll
                for (int t = 0; t < 8; ++t) {
                    bf16x8 bf = load_col8(Wkh + (size_t)d0 * DD + t * 16 + ml, DD);
                    acc[t] = MFMA(a, bf, acc[t]);
                }
            }
            ushort_t* dst = Abf + (size_t)h * DD * DD;
#pragma unroll
            for (int t = 0; t < 8; ++t)
#pragma unroll
                for (int r = 0; r < 4; ++r)
                    dst[(size_t)(w * 16 + quad * 4 + r) * DD + t * 16 + ml] =
                        (ushort_t)f2bf(acc[t][r]);
        } else {
#pragma unroll
            for (int kc = 0; kc < 2; ++kc) {
                const int e0 = kc * 32 + quad * 8;
                bf16x8 a = load_row8(Wo + (size_t)(w * 16 + ml) * INNER + h * DHH + e0);
#pragma unroll
                for (int t = 0; t < 8; ++t) {
                    bf16x8 bf = load_col8(Wkh + (size_t)e0 * DD + t * 16 + ml, DD);
                    acc[t] = MFMA(a, bf, acc[t]);
                }
            }
            ushort_t* dst = BTbf + (size_t)h * DD * DD;
#pragma unroll
            for (int t = 0; t < 8; ++t)
#pragma unroll
                for (int r = 0; r < 4; ++r)
                    dst[(size_t)(w * 16 + quad * 4 + r) * DD + t * 16 + ml] =
                        (ushort_t)f2bf(acc[t][r]);
        }
    }
}

// ---------------------------------------------------------------------------
// K2: reduce PC bf16 partials (fp32 accum) -> SbfT (bf16, TRANSPOSED:
// SbfT[c''][c] = S[c][c'']) — K3-stage1's B-fragment layout.
// 256 blocks x 128 threads. partial is L2-warm from K1 — normal loads.
// ---------------------------------------------------------------------------
__global__ __launch_bounds__(128) void k2_reduce(
        const ushort_t* __restrict__ partial, ushort_t* __restrict__ SbfT) {
    const int tid = blockIdx.x * 128 + threadIdx.x;  // 0..32767
    const int e   = tid * 2;
    const int b   = e >> 14;
    const int idx = e & 16383;
    const unsigned* p32 =
        (const unsigned*)(partial + ((size_t)b * PC) * DD * DD + idx);
    float s0 = 0.f, s1 = 0.f;
#pragma unroll 16
    for (int c = 0; c < PC; ++c) {
        const unsigned u = p32[(size_t)c * (DD * DD / 2)];
        s0 += bf2f((ushort_t)(u & 0xffffu));
        s1 += bf2f((ushort_t)(u >> 16));
    }
    const int c  = idx >> 7;    // S row
    const int cp = idx & 127;   // S col (this thread owns cp, cp+1)
    ushort_t* st = SbfT + (size_t)b * DD * DD;
    st[(size_t)(cp    ) * DD + c] = (ushort_t)f2bf(s0);
    st[(size_t)(cp + 1) * DD + c] = (ushort_t)f2bf(s1);
}

// ---------------------------------------------------------------------------
// K3: G[b][m0:m0+16][:] += A_h[m0:m0+16][:] @ S[b] @ B'_h.
// 256 blocks (b, h, 16-row m-strip); wave w owns n-tile w in both stages.
// Unchanged.
// ---------------------------------------------------------------------------
__global__ __launch_bounds__(512) void k3_middle(
        const ushort_t* __restrict__ SbfT, const ushort_t* __restrict__ Abf,
        const ushort_t* __restrict__ BTbf, float* __restrict__ G) {
    const int bi = blockIdx.x;           // 0..255
    const int b  = bi >> 6;
    const int h  = (bi >> 3) & 7;
    const int m0 = (bi & 7) * 16;
    const int lane = threadIdx.x & 63;
    const int w    = threadIdx.x >> 6;   // 0..7 -> n-tile w
    const int ml   = lane & 15;
    const int quad = lane >> 4;

    __shared__ short T[16 * 136];        // T[mr][c''], pitch 136 (b128-aligned)

    const ushort_t* Sb = SbfT + (size_t)b * DD * DD;
    const ushort_t* Ah = Abf  + (size_t)h * DD * DD;
    const ushort_t* Bh = BTbf + (size_t)h * DD * DD;

    // stage1: T = A_h[m0:m0+16] @ S   (B[k=c][n=c''] = SbfT[c''][c] rows)
    {
        f32x4 acc = (f32x4){0.f, 0.f, 0.f, 0.f};
#pragma unroll
        for (int kc = 0; kc < 4; ++kc) {
            const int c0 = kc * 32 + quad * 8;
            bf16x8 a  = *(const bf16x8*)&Ah[(size_t)(m0 + ml) * DD + c0];
            bf16x8 bf = *(const bf16x8*)&Sb[(size_t)(w * 16 + ml) * DD + c0];
            acc = MFMA(a, bf, acc);
        }
#pragma unroll
        for (int r = 0; r < 4; ++r)
            T[(quad * 4 + r) * 136 + w * 16 + ml] = f2bf(acc[r]);
    }
    __syncthreads();

    // stage2: G[m0:m0+16] += T @ B'_h  (B[k=cin][n=cout] = BT[cout][cin] rows)
    {
        f32x4 acc = (f32x4){0.f, 0.f, 0.f, 0.f};
#pragma unroll
        for (int kc = 0; kc < 4; ++kc) {
            const int k0 = kc * 32 + quad * 8;
            bf16x8 a  = *(const bf16x8*)&T[ml * 136 + k0];
            bf16x8 bf = *(const bf16x8*)&Bh[(size_t)(w * 16 + ml) * DD + k0];
            acc = MFMA(a, bf, acc);
        }
        float* Gb = G + (size_t)b * DD * DD;
#pragma unroll
        for (int r = 0; r < 4; ++r)
            atomicAdd(&Gb[(m0 + quad * 4 + r) * DD + w * 16 + ml], acc[r]);
    }
}

// ---------------------------------------------------------------------------
// K4: out[b] = queries[b] @ (G[b]/N) + bo.
//   R7: queries loaded non-temporal (read once); out stored non-temporal
//   (never re-read). Same MSHR-bypass theory as K1.
// 512 blocks x 512 threads, 128 rows per block (2 blocks/CU).
// ---------------------------------------------------------------------------
__global__ __launch_bounds__(512, 4) void k4_final(
        const float* __restrict__ queries, const float* __restrict__ G,
        const float* __restrict__ bo, float* __restrict__ outp) {
    const int b  = blockIdx.x >> 7;
    const int r0 = (blockIdx.x & 127) * 128;

    __shared__ short Gt[128 * 136];   // Gt[c][c'] = G[c'][c] * invN (B-layout)
    {
        const float* Gb = G + (size_t)b * DD * DD;
        const float invN = 6.103515625e-05f;  // 1/16384
#pragma unroll 4
        for (int it = 0; it < 32; ++it) {
            const int idx = (int)threadIdx.x + it * 512;
            const int cp = idx >> 7, c = idx & 127;
            Gt[c * 136 + cp] = f2bf(Gb[idx] * invN);
        }
    }
    __syncthreads();

    const int lane = threadIdx.x & 63;
    const int w    = threadIdx.x >> 6;   // 0..7 -> m-tile w
    const int ml   = lane & 15;
    const int quad = lane >> 4;
    const float* qbase = queries + ((size_t)b * NN + r0) * DD;

    f32x4 acc[8];
#pragma unroll
    for (int t = 0; t < 8; ++t) acc[t] = (f32x4){0.f, 0.f, 0.f, 0.f};

#pragma unroll
    for (int kc = 0; kc < 4; ++kc) {
        const int k0 = kc * 32 + quad * 8;
        bf16x8 a = load_row8_nt(qbase + (size_t)(w * 16 + ml) * DD + k0);
#pragma unroll
        for (int t = 0; t < 8; ++t) {
            bf16x8 bf = *(const bf16x8*)&Gt[(t * 16 + ml) * 136 + k0];
            acc[t] = MFMA(a, bf, acc[t]);
        }
    }

    float* ob = outp + ((size_t)b * NN + r0) * DD;
#pragma unroll
    for (int t = 0; t < 8; ++t) {
        const int c = t * 16 + ml;
        const float boc = bo[c];
#pragma unroll
        for (int r = 0; r < 4; ++r)
            __builtin_nontemporal_store(
                acc[t][r] + boc,
                &ob[(size_t)(w * 16 + quad * 4 + r) * DD + c]);
    }
}

extern "C" void kernel_launch(void* const* d_in, const int* in_sizes, int n_in,
                              void* d_out, int out_size, void* d_ws, size_t ws_size,
                              hipStream_t stream) {
    const float* queries = (const float*)d_in[0];
    const float* keys    = (const float*)d_in[1];
    const float* values  = (const float*)d_in[2];
    const float* Wq      = (const float*)d_in[3];
    const float* Wk      = (const float*)d_in[4];
    const float* Wo      = (const float*)d_in[5];
    const float* bo      = (const float*)d_in[6];
    float* out = (float*)d_out;

    // ws: [SbfT bf16 (256 KiB region)][G f32][Abf][BTbf][partial]
    ushort_t* SbfT = (ushort_t*)d_ws;
    float* G = (float*)d_ws + (size_t)BB * DD * DD;   // after 256 KiB region
    ushort_t* Abf     = (ushort_t*)(G + (size_t)BB * DD * DD);
    ushort_t* BTbf    = Abf  + (size_t)HH * DD * DD;
    ushort_t* partial = BTbf + (size_t)HH * DD * DD;

    hipLaunchKernelGGL(k1_partialS_ab, dim3(BB * PC + 16), dim3(512), 0, stream,
                       keys, values, Wq, Wk, Wo, partial, Abf, BTbf, G);
    hipLaunchKernelGGL(k2_reduce, dim3(256), dim3(128), 0, stream,
                       partial, SbfT);
    hipLaunchKernelGGL(k3_middle, dim3(256), dim3(512), 0, stream,
                       SbfT, Abf, BTbf, G);
    hipLaunchKernelGGL(k4_final, dim3(512), dim3(512), 0, stream,
                       queries, G, bo, out);
}

// Round 8
// 158.960 us; speedup vs baseline: 1.0331x; 1.0331x over previous
//
#include <hip/hip_runtime.h>
#include <hip/hip_bf16.h>

#define BB    4
#define NN    16384
#define DD    128
#define HH    8
#define DHH   64
#define INNER 512
#define PC    128         // K^T V row-chunks per batch (K1 main grid = BB*PC = 512)

typedef __attribute__((ext_vector_type(8))) short bf16x8;
typedef __attribute__((ext_vector_type(4))) short short4_t;
typedef __attribute__((ext_vector_type(4))) float f32x4;
typedef unsigned short ushort_t;

#define MFMA(a, b, c) __builtin_amdgcn_mfma_f32_16x16x32_bf16((a), (b), (c), 0, 0, 0)

// fp32 -> bf16 round-to-nearest-even
__device__ __forceinline__ short f2bf(float x) {
    union { float f; unsigned u; } v; v.f = x;
    unsigned u = v.u;
    u += 0x7fffu + ((u >> 16) & 1u);
    return (short)(u >> 16);
}

__device__ __forceinline__ float bf2f(ushort_t us) {
    union { unsigned u; float f; } v;
    v.u = ((unsigned)us) << 16;
    return v.f;
}

__device__ __forceinline__ bf16x8 load_row8(const float* __restrict__ p) {
    f32x4 a = *(const f32x4*)p;
    f32x4 b = *(const f32x4*)(p + 4);
    bf16x8 r;
    r[0] = f2bf(a[0]); r[1] = f2bf(a[1]); r[2] = f2bf(a[2]); r[3] = f2bf(a[3]);
    r[4] = f2bf(b[0]); r[5] = f2bf(b[1]); r[6] = f2bf(b[2]); r[7] = f2bf(b[3]);
    return r;
}

__device__ __forceinline__ bf16x8 load_col8(const float* __restrict__ p, int stride) {
    bf16x8 r;
#pragma unroll
    for (int j = 0; j < 8; ++j) r[j] = f2bf(p[(size_t)j * stride]);
    return r;
}

// ---------------------------------------------------------------------------
// K1: blocks [0,512): partial S[b] = keys^T @ values over a 128-row chunk.
//   PC=128 -> 2 blocks/CU; LDS staging + issue-early/write-late ordering.
//   NOTE (R5-R7 evidence): four structurally distinct variants (scalar
//   global, this one, raw-barrier counted-vmcnt pipeline, nt loads) all
//   measure the same — K1 is latency-bound on LLC-cold streams (the 256MiB
//   harness poison fill thrashes the LLC each iteration). This is the
//   best-measured form; do not re-litigate without new counter evidence.
// Blocks [512,528): head-factor producers (weights only) + G zeroing.
// ---------------------------------------------------------------------------
__global__ __launch_bounds__(512, 4) void k1_partialS_ab(
        const float* __restrict__ keys, const float* __restrict__ vals,
        const float* __restrict__ Wq, const float* __restrict__ Wk,
        const float* __restrict__ Wo,
        ushort_t* __restrict__ partial, ushort_t* __restrict__ Abf,
        ushort_t* __restrict__ BTbf, float* __restrict__ G) {
    const int lane = threadIdx.x & 63;
    const int w    = threadIdx.x >> 6;   // 0..7
    const int ml   = lane & 15;
    const int quad = lane >> 4;

    __shared__ short tK[2][32][132];     // pitch 132: b64-aligned writes
    __shared__ short tV[2][32][132];

    if (blockIdx.x < BB * PC) {
        const int b     = blockIdx.x >> 7;
        const int chunk = blockIdx.x & (PC - 1);
        const int r0    = chunk * (NN / PC);      // 128 rows per block
        const int mw    = w & 3;
        const int nw    = w >> 2;

        const float* kbase = keys + (size_t)b * NN * DD;
        const float* vbase = vals + (size_t)b * NN * DD;

        const int lin0 = (int)threadIdx.x;
        const int ca0  = (2 * mw + 0) * 16 + ml;
        const int ca1  = (2 * mw + 1) * 16 + ml;

        f32x4 acc[2][4];
#pragma unroll
        for (int i = 0; i < 2; ++i)
#pragma unroll
            for (int t = 0; t < 4; ++t) acc[i][t] = (f32x4){0.f, 0.f, 0.f, 0.f};

        // prologue: stage rows [r0, r0+32) into buffer 0
        {
            const float* kp = kbase + (size_t)r0 * DD;
            const float* vp = vbase + (size_t)r0 * DD;
#pragma unroll
            for (int it = 0; it < 2; ++it) {
                const int lin = lin0 + it * 512;
                const int row = lin >> 5;
                const int c4  = (lin & 31) << 2;
                f32x4 kk = *(const f32x4*)(kp + (size_t)row * DD + c4);
                f32x4 vv = *(const f32x4*)(vp + (size_t)row * DD + c4);
                short4_t ks, vs;
#pragma unroll
                for (int j = 0; j < 4; ++j) { ks[j] = f2bf(kk[j]); vs[j] = f2bf(vv[j]); }
                *(short4_t*)&tK[0][row][c4] = ks;
                *(short4_t*)&tV[0][row][c4] = vs;
            }
        }
        __syncthreads();

        for (int s = 0; s < 4; ++s) {             // 4 steps x 32 rows = 128
            const int cur   = s & 1;
            const bool more = (s < 3);

            // issue next tile's global loads BEFORE compute
            f32x4 kreg[2], vreg[2];
            if (more) {
                const float* kp = kbase + (size_t)(r0 + (s + 1) * 32) * DD;
                const float* vp = vbase + (size_t)(r0 + (s + 1) * 32) * DD;
#pragma unroll
                for (int it = 0; it < 2; ++it) {
                    const int lin = lin0 + it * 512;
                    const int row = lin >> 5;
                    const int c4  = (lin & 31) << 2;
                    kreg[it] = *(const f32x4*)(kp + (size_t)row * DD + c4);
                    vreg[it] = *(const f32x4*)(vp + (size_t)row * DD + c4);
                }
            }

            // compute on current buffer
            {
                bf16x8 a0, a1;
#pragma unroll
                for (int j = 0; j < 8; ++j) {
                    a0[j] = tK[cur][quad * 8 + j][ca0];
                    a1[j] = tK[cur][quad * 8 + j][ca1];
                }
#pragma unroll
                for (int t = 0; t < 4; ++t) {
                    const int cb = (nw * 4 + t) * 16 + ml;
                    bf16x8 bf;
#pragma unroll
                    for (int j = 0; j < 8; ++j) bf[j] = tV[cur][quad * 8 + j][cb];
                    acc[0][t] = MFMA(a0, bf, acc[0][t]);
                    acc[1][t] = MFMA(a1, bf, acc[1][t]);
                }
            }

            // convert + ds_write AFTER compute
            if (more) {
                __syncthreads();
                const int nb = cur ^ 1;
#pragma unroll
                for (int it = 0; it < 2; ++it) {
                    const int lin = lin0 + it * 512;
                    const int row = lin >> 5;
                    const int c4  = (lin & 31) << 2;
                    short4_t ks, vs;
#pragma unroll
                    for (int j = 0; j < 4; ++j) {
                        ks[j] = f2bf(kreg[it][j]);
                        vs[j] = f2bf(vreg[it][j]);
                    }
                    *(short4_t*)&tK[nb][row][c4] = ks;
                    *(short4_t*)&tV[nb][row][c4] = vs;
                }
                __syncthreads();
            }
        }

        ushort_t* outp = partial + (size_t)blockIdx.x * DD * DD;
#pragma unroll
        for (int i = 0; i < 2; ++i) {
            const int mrow = (2 * mw + i) * 16 + quad * 4;
#pragma unroll
            for (int t = 0; t < 4; ++t) {
                const int col = (nw * 4 + t) * 16 + ml;
#pragma unroll
                for (int r = 0; r < 4; ++r)
                    outp[(size_t)(mrow + r) * DD + col] = (ushort_t)f2bf(acc[i][t][r]);
            }
        }
    } else {
        // ---- head-factor producer (weights only) + G zeroing ----
        const int ab    = blockIdx.x - BB * PC;   // 0..15
        const int h     = ab & 7;
        const int which = ab >> 3;                // 0 -> A_h, 1 -> BT_h
        const float* Wkh = Wk + (size_t)h * DHH * DD;

        // zero G: 16 blocks x 512 threads x 8 floats = 65536 = BB*DD*DD
        {
            const int base = (ab * 512 + (int)threadIdx.x) * 8;
            *(f32x4*)&G[base]     = (f32x4){0.f, 0.f, 0.f, 0.f};
            *(f32x4*)&G[base + 4] = (f32x4){0.f, 0.f, 0.f, 0.f};
        }

        f32x4 acc[8];
#pragma unroll
        for (int t = 0; t < 8; ++t) acc[t] = (f32x4){0.f, 0.f, 0.f, 0.f};

        if (which == 0) {
            const float* Wqh = Wq + (size_t)h * DHH * DD;
#pragma unroll
            for (int kc = 0; kc < 2; ++kc) {
                const int d0 = kc * 32 + quad * 8;
                bf16x8 a = load_col8(Wqh + (size_t)d0 * DD + w * 16 + ml, DD);
#pragma unroll
                for (int t = 0; t < 8; ++t) {
                    bf16x8 bf = load_col8(Wkh + (size_t)d0 * DD + t * 16 + ml, DD);
                    acc[t] = MFMA(a, bf, acc[t]);
                }
            }
            ushort_t* dst = Abf + (size_t)h * DD * DD;
#pragma unroll
            for (int t = 0; t < 8; ++t)
#pragma unroll
                for (int r = 0; r < 4; ++r)
                    dst[(size_t)(w * 16 + quad * 4 + r) * DD + t * 16 + ml] =
                        (ushort_t)f2bf(acc[t][r]);
        } else {
#pragma unroll
            for (int kc = 0; kc < 2; ++kc) {
                const int e0 = kc * 32 + quad * 8;
                bf16x8 a = load_row8(Wo + (size_t)(w * 16 + ml) * INNER + h * DHH + e0);
#pragma unroll
                for (int t = 0; t < 8; ++t) {
                    bf16x8 bf = load_col8(Wkh + (size_t)e0 * DD + t * 16 + ml, DD);
                    acc[t] = MFMA(a, bf, acc[t]);
                }
            }
            ushort_t* dst = BTbf + (size_t)h * DD * DD;
#pragma unroll
            for (int t = 0; t < 8; ++t)
#pragma unroll
                for (int r = 0; r < 4; ++r)
                    dst[(size_t)(w * 16 + quad * 4 + r) * DD + t * 16 + ml] =
                        (ushort_t)f2bf(acc[t][r]);
        }
    }
}

// ---------------------------------------------------------------------------
// K2: reduce PC bf16 partials (fp32 accum) -> SbfT (bf16, TRANSPOSED:
// SbfT[c''][c] = S[c][c'']) — K3-stage1's B-fragment layout.
// 256 blocks x 128 threads (full machine).
// ---------------------------------------------------------------------------
__global__ __launch_bounds__(128) void k2_reduce(
        const ushort_t* __restrict__ partial, ushort_t* __restrict__ SbfT) {
    const int tid = blockIdx.x * 128 + threadIdx.x;  // 0..32767
    const int e   = tid * 2;
    const int b   = e >> 14;
    const int idx = e & 16383;
    const unsigned* p32 =
        (const unsigned*)(partial + ((size_t)b * PC) * DD * DD + idx);
    float s0 = 0.f, s1 = 0.f;
#pragma unroll 16
    for (int c = 0; c < PC; ++c) {
        const unsigned u = p32[(size_t)c * (DD * DD / 2)];
        s0 += bf2f((ushort_t)(u & 0xffffu));
        s1 += bf2f((ushort_t)(u >> 16));
    }
    const int c  = idx >> 7;    // S row
    const int cp = idx & 127;   // S col (this thread owns cp, cp+1)
    ushort_t* st = SbfT + (size_t)b * DD * DD;
    st[(size_t)(cp    ) * DD + c] = (ushort_t)f2bf(s0);
    st[(size_t)(cp + 1) * DD + c] = (ushort_t)f2bf(s1);
}

// ---------------------------------------------------------------------------
// K3: G[b][m0:m0+16][:] += A_h[m0:m0+16][:] @ S[b] @ B'_h.
// 256 blocks (b, h, 16-row m-strip); wave w owns n-tile w in both stages.
// ---------------------------------------------------------------------------
__global__ __launch_bounds__(512) void k3_middle(
        const ushort_t* __restrict__ SbfT, const ushort_t* __restrict__ Abf,
        const ushort_t* __restrict__ BTbf, float* __restrict__ G) {
    const int bi = blockIdx.x;           // 0..255
    const int b  = bi >> 6;
    const int h  = (bi >> 3) & 7;
    const int m0 = (bi & 7) * 16;
    const int lane = threadIdx.x & 63;
    const int w    = threadIdx.x >> 6;   // 0..7 -> n-tile w
    const int ml   = lane & 15;
    const int quad = lane >> 4;

    __shared__ short T[16 * 136];        // T[mr][c''], pitch 136 (b128-aligned)

    const ushort_t* Sb = SbfT + (size_t)b * DD * DD;
    const ushort_t* Ah = Abf  + (size_t)h * DD * DD;
    const ushort_t* Bh = BTbf + (size_t)h * DD * DD;

    // stage1: T = A_h[m0:m0+16] @ S   (B[k=c][n=c''] = SbfT[c''][c] rows)
    {
        f32x4 acc = (f32x4){0.f, 0.f, 0.f, 0.f};
#pragma unroll
        for (int kc = 0; kc < 4; ++kc) {
            const int c0 = kc * 32 + quad * 8;
            bf16x8 a  = *(const bf16x8*)&Ah[(size_t)(m0 + ml) * DD + c0];
            bf16x8 bf = *(const bf16x8*)&Sb[(size_t)(w * 16 + ml) * DD + c0];
            acc = MFMA(a, bf, acc);
        }
#pragma unroll
        for (int r = 0; r < 4; ++r)
            T[(quad * 4 + r) * 136 + w * 16 + ml] = f2bf(acc[r]);
    }
    __syncthreads();

    // stage2: G[m0:m0+16] += T @ B'_h  (B[k=cin][n=cout] = BT[cout][cin] rows)
    {
        f32x4 acc = (f32x4){0.f, 0.f, 0.f, 0.f};
#pragma unroll
        for (int kc = 0; kc < 4; ++kc) {
            const int k0 = kc * 32 + quad * 8;
            bf16x8 a  = *(const bf16x8*)&T[ml * 136 + k0];
            bf16x8 bf = *(const bf16x8*)&Bh[(size_t)(w * 16 + ml) * DD + k0];
            acc = MFMA(a, bf, acc);
        }
        float* Gb = G + (size_t)b * DD * DD;
#pragma unroll
        for (int r = 0; r < 4; ++r)
            atomicAdd(&Gb[(m0 + quad * 4 + r) * DD + w * 16 + ml], acc[r]);
    }
}

// ---------------------------------------------------------------------------
// K4: out[b] = queries[b] @ (G[b]/N) + bo.
// 512 blocks x 512 threads, 128 rows per block (2 blocks/CU).
// Plain cached loads/stores (R7 showed nt HURTS: it discards the partial
// LLC residency of queries between iterations).
// ---------------------------------------------------------------------------
__global__ __launch_bounds__(512, 4) void k4_final(
        const float* __restrict__ queries, const float* __restrict__ G,
        const float* __restrict__ bo, float* __restrict__ outp) {
    const int b  = blockIdx.x >> 7;
    const int r0 = (blockIdx.x & 127) * 128;

    __shared__ short Gt[128 * 136];   // Gt[c][c'] = G[c'][c] * invN (B-layout)
    {
        const float* Gb = G + (size_t)b * DD * DD;
        const float invN = 6.103515625e-05f;  // 1/16384
#pragma unroll 4
        for (int it = 0; it < 32; ++it) {
            const int idx = (int)threadIdx.x + it * 512;
            const int cp = idx >> 7, c = idx & 127;
            Gt[c * 136 + cp] = f2bf(Gb[idx] * invN);
        }
    }
    __syncthreads();

    const int lane = threadIdx.x & 63;
    const int w    = threadIdx.x >> 6;   // 0..7 -> m-tile w
    const int ml   = lane & 15;
    const int quad = lane >> 4;
    const float* qbase = queries + ((size_t)b * NN + r0) * DD;

    f32x4 acc[8];
#pragma unroll
    for (int t = 0; t < 8; ++t) acc[t] = (f32x4){0.f, 0.f, 0.f, 0.f};

#pragma unroll
    for (int kc = 0; kc < 4; ++kc) {
        const int k0 = kc * 32 + quad * 8;
        bf16x8 a = load_row8(qbase + (size_t)(w * 16 + ml) * DD + k0);
#pragma unroll
        for (int t = 0; t < 8; ++t) {
            bf16x8 bf = *(const bf16x8*)&Gt[(t * 16 + ml) * 136 + k0];
            acc[t] = MFMA(a, bf, acc[t]);
        }
    }

    float* ob = outp + ((size_t)b * NN + r0) * DD;
#pragma unroll
    for (int t = 0; t < 8; ++t) {
        const int c = t * 16 + ml;
        const float boc = bo[c];
#pragma unroll
        for (int r = 0; r < 4; ++r)
            ob[(size_t)(w * 16 + quad * 4 + r) * DD + c] = acc[t][r] + boc;
    }
}

extern "C" void kernel_launch(void* const* d_in, const int* in_sizes, int n_in,
                              void* d_out, int out_size, void* d_ws, size_t ws_size,
                              hipStream_t stream) {
    const float* queries = (const float*)d_in[0];
    const float* keys    = (const float*)d_in[1];
    const float* values  = (const float*)d_in[2];
    const float* Wq      = (const float*)d_in[3];
    const float* Wk      = (const float*)d_in[4];
    const float* Wo      = (const float*)d_in[5];
    const float* bo      = (const float*)d_in[6];
    float* out = (float*)d_out;

    // ws: [SbfT bf16 (256 KiB region)][G f32][Abf][BTbf][partial]
    ushort_t* SbfT = (ushort_t*)d_ws;
    float* G = (float*)d_ws + (size_t)BB * DD * DD;   // after 256 KiB region
    ushort_t* Abf     = (ushort_t*)(G + (size_t)BB * DD * DD);
    ushort_t* BTbf    = Abf  + (size_t)HH * DD * DD;
    ushort_t* partial = BTbf + (size_t)HH * DD * DD;

    hipLaunchKernelGGL(k1_partialS_ab, dim3(BB * PC + 16), dim3(512), 0, stream,
                       keys, values, Wq, Wk, Wo, partial, Abf, BTbf, G);
    hipLaunchKernelGGL(k2_reduce, dim3(256), dim3(128), 0, stream,
                       partial, SbfT);
    hipLaunchKernelGGL(k3_middle, dim3(256), dim3(512), 0, stream,
                       SbfT, Abf, BTbf, G);
    hipLaunchKernelGGL(k4_final, dim3(512), dim3(512), 0, stream,
                       queries, G, bo, out);
}